// Round 20
// baseline (166.141 us; speedup 1.0000x reference)
//
#include <hip/hip_runtime.h>

typedef __attribute__((ext_vector_type(8))) short short8;
typedef __attribute__((ext_vector_type(4))) float f32x4;

#define T_ 1024
#define D_ 64
#define CSC 0.18033688f   // 0.125 * log2(e)

static __device__ __forceinline__ unsigned short f2bf(float f) {
    union { float f; unsigned u; } x; x.f = f;
    unsigned r = x.u + 0x7fffu + ((x.u >> 16) & 1u);
    return (unsigned short)(r >> 16);
}
static __device__ __forceinline__ float fexp2(float x) {
    return __builtin_amdgcn_exp2f(fminf(x, 60.f));
}
// async global->LDS, 16B per lane; LDS dest is wave-uniform base + lane*16
static __device__ __forceinline__ void gload16(const unsigned short* g, unsigned short* l) {
    __builtin_amdgcn_global_load_lds(
        (__attribute__((address_space(1))) void*)g,
        (__attribute__((address_space(3))) void*)l, 16, 0, 0);
}

// ================= pre-kernel: K -> bf16, V -> V^T bf16 (into ws) ============
__global__ __launch_bounds__(256) void preconv(
    const float* __restrict__ kg, const float* __restrict__ vg,
    unsigned short* __restrict__ kbf, unsigned short* __restrict__ vtb)
{
    __shared__ float vt[64][65];
    const int tid = threadIdx.x;
    const int bh = blockIdx.x >> 4, tile = blockIdx.x & 15;
    const long eb = (long)bh * (T_ * D_) + tile * 64 * D_;
    const int r = tid >> 2, d0 = (tid & 3) * 16;

    {   // K convert (row-major bf16; main kernel pre-swizzles its source addr)
        const float* s = kg + eb + r * 64 + d0;
        f32x4 a0 = *(const f32x4*)(s + 0);
        f32x4 a1 = *(const f32x4*)(s + 4);
        f32x4 a2 = *(const f32x4*)(s + 8);
        f32x4 a3 = *(const f32x4*)(s + 12);
        short8 p0, p1;
        #pragma unroll
        for (int i = 0; i < 4; ++i) {
            p0[i]     = (short)f2bf(a0[i]); p0[4 + i] = (short)f2bf(a1[i]);
            p1[i]     = (short)f2bf(a2[i]); p1[4 + i] = (short)f2bf(a3[i]);
        }
        *(short8*)&kbf[eb + r * 64 + d0]     = p0;
        *(short8*)&kbf[eb + r * 64 + d0 + 8] = p1;
    }
    {   // V tile -> LDS transposed (fp32)
        const float* s = vg + eb + r * 64 + d0;
        f32x4 a0 = *(const f32x4*)(s + 0);
        f32x4 a1 = *(const f32x4*)(s + 4);
        f32x4 a2 = *(const f32x4*)(s + 8);
        f32x4 a3 = *(const f32x4*)(s + 12);
        #pragma unroll
        for (int i = 0; i < 4; ++i) {
            vt[d0 + i][r]      = a0[i];
            vt[d0 + 4 + i][r]  = a1[i];
            vt[d0 + 8 + i][r]  = a2[i];
            vt[d0 + 12 + i][r] = a3[i];
        }
    }
    __syncthreads();
    {   // V^T rows out (coalesced), bf16
        short8 p0, p1;
        #pragma unroll
        for (int i = 0; i < 8; ++i) {
            p0[i] = (short)f2bf(vt[r][d0 + i]);
            p1[i] = (short)f2bf(vt[r][d0 + 8 + i]);
        }
        const long vb = ((long)bh * D_ + r) * T_ + tile * 64 + d0;
        *(short8*)&vtb[vb]     = p0;
        *(short8*)&vtb[vb + 8] = p1;
    }
}

// ==== main kernel: 40960B LDS (4 blocks/CU, zero tail) + counted-vmcnt =======
__global__ __launch_bounds__(256, 3) void relattn(
    const float* __restrict__ qg,
    const unsigned short* __restrict__ kbf,   // [bh][1024][64] bf16
    const unsigned short* __restrict__ vtb,   // [bh][64][1024] bf16 (V^T)
    const float* __restrict__ embk,
    const float* __restrict__ embv,
    float* __restrict__ outg, float* __restrict__ attng)
{
    // 40960 B exactly -> LDS allows 4 blocks/CU; (256,3) bound keeps VGPR=84
    // (no spill) and HW still co-schedules 4 blocks (4 waves/SIMD x 84 <= 512).
    __shared__ __align__(16) unsigned char lds[40960];
    unsigned short* QPt   = (unsigned short*)(lds);           // [0,8192): Q -> P (wave-private rows)
    unsigned short* Kb    = (unsigned short*)(lds + 8192);    // [8192,24576): K dbuf
    unsigned short* Vt    = (unsigned short*)(lds + 24576);   // [24576,32768): V^T single
    _Float16*       biasH = (_Float16*)(lds + 32768);         // [32768,36992): fp16 [64][33]
    _Float16*       wS    = (_Float16*)(lds + 36992);         // [36992,40960): fp16 [64][31]
    float*          embvS = (float*)(lds);                    // epilogue alias (QPt/Kb dead)

    const int tid  = threadIdx.x;
    const int lane = tid & 63;
    const int wv   = tid >> 6;
    const int g16  = lane >> 4;
    const int l16  = lane & 15;
    const int rbase = wv * 16 + g16 * 4;

    const int lg = ((blockIdx.x & 7) << 7) | (blockIdx.x >> 3);
    const int bh = lg >> 4;
    const int t0 = (lg & 15) * 64;
    const int dtile = t0 >> 6;
    const long base = (long)bh * (T_ * D_);

    // per-lane pre-swizzled source offsets (elem units); same involution the
    // frag reader applies: group g at row r reads source group g^(r&7).
    int kofs0, kofs1, vofs0, vofs1;
    {
        const int gg = lane & 7, lr = lane >> 3;
        const int r0 = (wv * 2) * 8 + lr, r1 = (wv * 2 + 1) * 8 + lr;
        kofs0 = r0 * 64   + ((gg ^ (r0 & 7)) << 3);
        kofs1 = r1 * 64   + ((gg ^ (r1 & 7)) << 3);
        vofs0 = r0 * 1024 + ((gg ^ (r0 & 7)) << 3);
        vofs1 = r1 * 1024 + ((gg ^ (r1 & 7)) << 3);
    }
    const unsigned short* kbh = kbf + base;
    const unsigned short* vbh = vtb + base;
    unsigned short* kdst = Kb + wv * 1024;   // slot base (wave-uniform)
    unsigned short* vdst = Vt + wv * 1024;

    // ---------- prologue: Q stage + wS zero ----------
    {
        const int r = tid >> 2, d0 = (tid & 3) * 16;
        const float* s = qg + base + (long)t0 * D_ + r * 64 + d0;
        f32x4 a0 = *(const f32x4*)(s + 0);
        f32x4 a1 = *(const f32x4*)(s + 4);
        f32x4 a2 = *(const f32x4*)(s + 8);
        f32x4 a3 = *(const f32x4*)(s + 12);
        short8 p0, p1;
        #pragma unroll
        for (int i = 0; i < 4; ++i) {
            p0[i]     = (short)f2bf(a0[i]); p0[4 + i] = (short)f2bf(a1[i]);
            p1[i]     = (short)f2bf(a2[i]); p1[4 + i] = (short)f2bf(a3[i]);
        }
        const int sw = (r & 7) << 3;
        *(short8*)&QPt[(r * 64 + d0)     ^ sw] = p0;
        *(short8*)&QPt[(r * 64 + d0 + 8) ^ sw] = p1;
    }
    for (int i = tid; i < 64 * 31; i += 256) wS[i] = (_Float16)0.f;
    __syncthreads();

    // issue K tile 0 (latency hides under bias compute)
    gload16(kbh + kofs0, kdst);
    gload16(kbh + kofs1, kdst + 512);

    // bias[r][j] = CSC * (q_fp32 . emb_k[j]) -> fp16 (10-bit mantissa)
    for (int p = tid; p < 64 * 33; p += 256) {
        const int r = p / 33, j = p - r * 33;
        const float* qr = qg + base + (long)(t0 + r) * D_;
        const float* er = embk + j * D_;
        float acc = 0.f;
        #pragma unroll
        for (int d = 0; d < 64; d += 4) {
            f32x4 a = *(const f32x4*)(qr + d);
            f32x4 b = *(const f32x4*)(er + d);
            acc += a[0] * b[0] + a[1] * b[1] + a[2] * b[2] + a[3] * b[3];
        }
        biasH[r * 33 + j] = (_Float16)(acc * CSC);
    }

    short8 qfrag[2];
    {
        const int r = wv * 16 + l16;
        const int sw = (r & 7) << 3;
        qfrag[0] = *(short8*)&QPt[((r * 64 + 0  + g16 * 8) ^ sw)];
        qfrag[1] = *(short8*)&QPt[((r * 64 + 32 + g16 * 8) ^ sw)];
    }
    __syncthreads();   // biasH visible; K0 landed (vmcnt drain)

    float bias_m[4], bias_p[4];
    #pragma unroll
    for (int j = 0; j < 4; ++j) {
        bias_m[j] = (float)biasH[(rbase + j) * 33 + 0];
        bias_p[j] = (float)biasH[(rbase + j) * 33 + 32];
    }

    // ---------- sweep 1: Z only; K dbuf, 1 syncthreads/iter (validated) ----------
    float zacc[4] = {0.f, 0.f, 0.f, 0.f};
    for (int tile = 0; tile < 16; ++tile) {
        unsigned short* Kc = Kb + ((tile & 1) << 12);
        if (tile < 15) {
            unsigned short* kn = Kb + (((tile + 1) & 1) << 12) + wv * 1024;
            gload16(kbh + (tile + 1) * 4096 + kofs0, kn);
            gload16(kbh + (tile + 1) * 4096 + kofs1, kn + 512);
        }
        f32x4 acc[4];
        #pragma unroll
        for (int sc = 0; sc < 4; ++sc) {
            f32x4 a = {0.f, 0.f, 0.f, 0.f};
            #pragma unroll
            for (int ks = 0; ks < 2; ++ks) {
                const int r = sc * 16 + l16;
                short8 bf = *(short8*)&Kc[((r * 64 + ks * 32 + g16 * 8) ^ ((r & 7) << 3))];
                a = __builtin_amdgcn_mfma_f32_16x16x32_bf16(qfrag[ks], bf, a, 0, 0, 0);
            }
            acc[sc] = a;
        }
        if (tile < dtile - 1) {
            #pragma unroll
            for (int j = 0; j < 4; ++j)
                #pragma unroll
                for (int sc = 0; sc < 4; ++sc)
                    zacc[j] += fexp2(fmaf(acc[sc][j], CSC, bias_m[j]));
        } else if (tile > dtile + 1) {
            #pragma unroll
            for (int j = 0; j < 4; ++j)
                #pragma unroll
                for (int sc = 0; sc < 4; ++sc)
                    zacc[j] += fexp2(fmaf(acc[sc][j], CSC, bias_p[j]));
        } else {
            #pragma unroll
            for (int j = 0; j < 4; ++j) {
                const int rl = rbase + j;
                const int tg = t0 + rl;
                #pragma unroll
                for (int sc = 0; sc < 4; ++sc) {
                    const int sg = tile * 64 + sc * 16 + l16;
                    int dsr = sg - tg;
                    int dc = dsr < -16 ? -16 : (dsr > 16 ? 16 : dsr);
                    const float b = (float)biasH[rl * 33 + dc + 16];
                    zacc[j] += fexp2(fmaf(acc[sc][j], CSC, b));
                }
            }
        }
        __syncthreads();   // drains next-tile loads; all waves done with Kc
    }
    float iZ[4];
    #pragma unroll
    for (int j = 0; j < 4; ++j) {
        float z = zacc[j];
        #pragma unroll
        for (int o = 1; o < 16; o <<= 1) z += __shfl_xor(z, o);
        iZ[j] = 1.f / z;
    }

    // ---------- sweep 2 prologue: issue K0 ----------
    gload16(kbh + kofs0, kdst);
    gload16(kbh + kofs1, kdst + 512);
    __syncthreads();   // K0 landed

    // ---------- sweep 2: counted-vmcnt pipeline (attn stores never drained) ----
    f32x4 oacc[4];
    {
        f32x4 z = {0.f, 0.f, 0.f, 0.f};
        #pragma unroll
        for (int dc = 0; dc < 4; ++dc) oacc[dc] = z;
    }
    float ps0[4]  = {0.f, 0.f, 0.f, 0.f};
    float ps32[4] = {0.f, 0.f, 0.f, 0.f};
    float* attnB = attng + (long)bh * T_ * T_;

    for (int tile = 0; tile < 16; ++tile) {
        unsigned short* Kc = Kb + ((tile & 1) << 12);
        // issue V(t), then K(t+1) (order pinned; vmcnt counts depend on it)
        gload16(vbh + tile * 64 + vofs0, vdst);
        gload16(vbh + tile * 64 + vofs1, vdst + 512);
        __builtin_amdgcn_sched_barrier(0);
        if (tile < 15) {
            unsigned short* kn = Kb + (((tile + 1) & 1) << 12) + wv * 1024;
            gload16(kbh + (tile + 1) * 4096 + kofs0, kn);
            gload16(kbh + (tile + 1) * 4096 + kofs1, kn + 512);
        }
        __builtin_amdgcn_sched_barrier(0);

        // QK^T from Kc (landed at prev iter's B2)
        f32x4 acc[4];
        #pragma unroll
        for (int sc = 0; sc < 4; ++sc) {
            f32x4 a = {0.f, 0.f, 0.f, 0.f};
            #pragma unroll
            for (int ks = 0; ks < 2; ++ks) {
                const int r = sc * 16 + l16;
                short8 bf = *(short8*)&Kc[((r * 64 + ks * 32 + g16 * 8) ^ ((r & 7) << 3))];
                a = __builtin_amdgcn_mfma_f32_16x16x32_bf16(qfrag[ks], bf, a, 0, 0, 0);
            }
            acc[sc] = a;
        }

        // softmax + attn stores (16 dword stores/lane — stay in flight across B1/B2)
        if (tile < dtile - 1) {
            #pragma unroll
            for (int j = 0; j < 4; ++j) {
                const int rl = rbase + j;
                const int tg = t0 + rl;
                #pragma unroll
                for (int sc = 0; sc < 4; ++sc) {
                    const int sl = sc * 16 + l16;
                    const float a = fexp2(fmaf(acc[sc][j], CSC, bias_m[j])) * iZ[j];
                    attnB[(long)tg * T_ + tile * 64 + sl] = a;
                    QPt[((rl * 64 + sl) ^ ((rl & 7) << 3))] = f2bf(a);
                    ps0[j] += a;
                }
            }
        } else if (tile > dtile + 1) {
            #pragma unroll
            for (int j = 0; j < 4; ++j) {
                const int rl = rbase + j;
                const int tg = t0 + rl;
                #pragma unroll
                for (int sc = 0; sc < 4; ++sc) {
                    const int sl = sc * 16 + l16;
                    const float a = fexp2(fmaf(acc[sc][j], CSC, bias_p[j])) * iZ[j];
                    attnB[(long)tg * T_ + tile * 64 + sl] = a;
                    QPt[((rl * 64 + sl) ^ ((rl & 7) << 3))] = f2bf(a);
                    ps32[j] += a;
                }
            }
        } else {
            #pragma unroll
            for (int j = 0; j < 4; ++j) {
                const int rl = rbase + j;
                const int tg = t0 + rl;
                #pragma unroll
                for (int sc = 0; sc < 4; ++sc) {
                    const int sl = sc * 16 + l16;
                    const int sg = tile * 64 + sl;
                    const int dsr = sg - tg;
                    int dc = dsr < -16 ? -16 : (dsr > 16 ? 16 : dsr);
                    const float b = (float)biasH[rl * 33 + dc + 16];
                    const float a = fexp2(fmaf(acc[sc][j], CSC, b)) * iZ[j];
                    attnB[(long)tg * T_ + sg] = a;
                    QPt[((rl * 64 + sl) ^ ((rl & 7) << 3))] = f2bf(a);
                    if (dsr <= -16)      ps0[j]  += a;
                    else if (dsr >= 16)  ps32[j] += a;
                    else                 wS[rl * 31 + dsr + 15] = (_Float16)a;
                }
            }
        }

        // B1: V(t) landed. Outstanding younger: 2 K + 16 stores = 18 (tile 15: 16).
        if (tile < 15) asm volatile("s_waitcnt vmcnt(18) lgkmcnt(0)" ::: "memory");
        else           asm volatile("s_waitcnt vmcnt(16) lgkmcnt(0)" ::: "memory");
        __builtin_amdgcn_s_barrier();
        __builtin_amdgcn_sched_barrier(0);

        // PV: A = P (own wave rows, intra-wave dep), B = V^T
        #pragma unroll
        for (int ks = 0; ks < 2; ++ks) {
            const int rp = wv * 16 + l16;
            short8 pa = *(short8*)&QPt[((rp * 64 + ks * 32 + g16 * 8) ^ ((rp & 7) << 3))];
            #pragma unroll
            for (int dc = 0; dc < 4; ++dc) {
                const int rv = dc * 16 + l16;
                short8 vb = *(short8*)&Vt[((rv * 64 + ks * 32 + g16 * 8) ^ ((rv & 7) << 3))];
                oacc[dc] = __builtin_amdgcn_mfma_f32_16x16x32_bf16(pa, vb, oacc[dc], 0, 0, 0);
            }
        }

        // B2: K(t+1) landed (vmcnt 16: stores younger) AND this wave's Vt/Kc
        // ds_reads retired (lgkmcnt 0 — the R12 race fix) before buffer reuse.
        asm volatile("s_waitcnt vmcnt(16) lgkmcnt(0)" ::: "memory");
        __builtin_amdgcn_s_barrier();
        __builtin_amdgcn_sched_barrier(0);
    }

    // ---------- epilogue ----------
    for (int i = tid; i < 33 * 64; i += 256) embvS[i] = embv[i];

    float w0r[4], w32r[4];
    #pragma unroll
    for (int j = 0; j < 4; ++j) {
        float a0 = ps0[j], a2 = ps32[j];
        #pragma unroll
        for (int o = 1; o < 16; o <<= 1) {
            a0 += __shfl_xor(a0, o);
            a2 += __shfl_xor(a2, o);
        }
        w0r[j] = a0; w32r[j] = a2;
    }
    __syncthreads();   // embvS + wS visible (drains all residual ops)

    float vals[4][4];
    #pragma unroll
    for (int j = 0; j < 4; ++j)
        #pragma unroll
        for (int dc = 0; dc < 4; ++dc)
            vals[j][dc] = oacc[dc][j]
                        + w0r[j]  * embvS[0 * 64  + dc * 16 + l16]
                        + w32r[j] * embvS[32 * 64 + dc * 16 + l16];
    for (int jj = 1; jj < 32; ++jj) {
        float e[4];
        #pragma unroll
        for (int dc = 0; dc < 4; ++dc) e[dc] = embvS[jj * 64 + dc * 16 + l16];
        #pragma unroll
        for (int j = 0; j < 4; ++j) {
            const float w = (float)wS[(rbase + j) * 31 + jj - 1];
            #pragma unroll
            for (int dc = 0; dc < 4; ++dc) vals[j][dc] += w * e[dc];
        }
    }
    #pragma unroll
    for (int j = 0; j < 4; ++j) {
        const int tg = t0 + rbase + j;
        #pragma unroll
        for (int dc = 0; dc < 4; ++dc)
            outg[base + (long)tg * D_ + dc * 16 + l16] = vals[j][dc];
    }
}

// ================= fallback (R5-validated) if ws too small ===================
static __device__ __forceinline__ void stage64x64(const float* __restrict__ src,
                                                  unsigned short* dst, int tid) {
    const int r = tid >> 2, d0 = (tid & 3) * 16;
    const float* s = src + r * 64 + d0;
    __attribute__((aligned(16))) float tmp[16];
    *(float4*)(tmp + 0)  = *(const float4*)(s + 0);
    *(float4*)(tmp + 4)  = *(const float4*)(s + 4);
    *(float4*)(tmp + 8)  = *(const float4*)(s + 8);
    *(float4*)(tmp + 12) = *(const float4*)(s + 12);
    #pragma unroll
    for (int h = 0; h < 2; ++h) {
        short8 pk;
        #pragma unroll
        for (int i = 0; i < 8; ++i) pk[i] = (short)f2bf(tmp[h * 8 + i]);
        *(short8*)&dst[((r * 64 + d0 + h * 8) ^ ((r & 7) << 3))] = pk;
    }
}
static __device__ __forceinline__ void stage64x64T(const float* __restrict__ src,
                                                   unsigned short* dst, int tid) {
    const int r = tid >> 2, d0 = (tid & 3) * 16;
    const float* s = src + r * 64 + d0;
    __attribute__((aligned(16))) float tmp[16];
    *(float4*)(tmp + 0)  = *(const float4*)(s + 0);
    *(float4*)(tmp + 4)  = *(const float4*)(s + 4);
    *(float4*)(tmp + 8)  = *(const float4*)(s + 8);
    *(float4*)(tmp + 12) = *(const float4*)(s + 12);
    #pragma unroll
    for (int i = 0; i < 16; ++i) {
        const int dd = d0 + i;
        dst[((dd * 64 + r) ^ ((dd & 7) << 3))] = f2bf(tmp[i]);
    }
}

__global__ __launch_bounds__(256, 3) void relattn_fb(
    const float* __restrict__ qg, const float* __restrict__ kg,
    const float* __restrict__ vg, const float* __restrict__ embk,
    const float* __restrict__ embv,
    float* __restrict__ outg, float* __restrict__ attng)
{
    __shared__ __align__(16) unsigned short QPt[64 * 64];
    __shared__ __align__(16) unsigned short Kt[64 * 64];
    __shared__ __align__(16) unsigned short Vt[64 * 64];
    __shared__ float biasS[64 * 34];
    __shared__ float wS[64 * 33];
    __shared__ float embvS[33 * 64];

    const int tid  = threadIdx.x;
    const int lane = tid & 63;
    const int wv   = tid >> 6;
    const int g16  = lane >> 4;
    const int l16  = lane & 15;
    const int rbase = wv * 16 + g16 * 4;

    const int lg = ((blockIdx.x & 7) << 7) | (blockIdx.x >> 3);
    const int bh = lg >> 4;
    const int t0 = (lg & 15) * 64;
    const int dtile = t0 >> 6;
    const long base = (long)bh * (T_ * D_);

    stage64x64(qg + base + (long)t0 * D_, QPt, tid);
    for (int i = tid; i < 33 * 64; i += 256) embvS[i] = embv[i];
    for (int i = tid; i < 64 * 33; i += 256) wS[i] = 0.f;
    __syncthreads();

    for (int p = tid; p < 64 * 33; p += 256) {
        const int r = p / 33, j = p - r * 33;
        const float* qr = qg + base + (long)(t0 + r) * D_;
        const float* er = embk + j * D_;
        float acc = 0.f;
        #pragma unroll
        for (int d = 0; d < 64; d += 4) {
            f32x4 a = *(const f32x4*)(qr + d);
            f32x4 b = *(const f32x4*)(er + d);
            acc += a[0] * b[0] + a[1] * b[1] + a[2] * b[2] + a[3] * b[3];
        }
        biasS[r * 34 + j] = acc * CSC;
    }
    short8 qfrag[2];
    {
        const int r = wv * 16 + l16;
        const int sw = (r & 7) << 3;
        qfrag[0] = *(short8*)&QPt[((r * 64 + 0  + g16 * 8) ^ sw)];
        qfrag[1] = *(short8*)&QPt[((r * 64 + 32 + g16 * 8) ^ sw)];
    }
    __syncthreads();

    float bias_m[4], bias_p[4];
    #pragma unroll
    for (int j = 0; j < 4; ++j) {
        bias_m[j] = biasS[(rbase + j) * 34 + 0];
        bias_p[j] = biasS[(rbase + j) * 34 + 32];
    }

    float zacc[4] = {0.f, 0.f, 0.f, 0.f};
    for (int tile = 0; tile < 16; ++tile) {
        stage64x64(kg + base + (long)tile * 64 * D_, Kt, tid);
        __syncthreads();
        f32x4 acc[4];
        #pragma unroll
        for (int sc = 0; sc < 4; ++sc) {
            f32x4 a = {0.f, 0.f, 0.f, 0.f};
            #pragma unroll
            for (int ks = 0; ks < 2; ++ks) {
                const int r = sc * 16 + l16;
                short8 bf = *(short8*)&Kt[((r * 64 + ks * 32 + g16 * 8) ^ ((r & 7) << 3))];
                a = __builtin_amdgcn_mfma_f32_16x16x32_bf16(qfrag[ks], bf, a, 0, 0, 0);
            }
            acc[sc] = a;
        }
        if (tile < dtile - 1) {
            #pragma unroll
            for (int j = 0; j < 4; ++j)
                #pragma unroll
                for (int sc = 0; sc < 4; ++sc)
                    zacc[j] += fexp2(fmaf(acc[sc][j], CSC, bias_m[j]));
        } else if (tile > dtile + 1) {
            #pragma unroll
            for (int j = 0; j < 4; ++j)
                #pragma unroll
                for (int sc = 0; sc < 4; ++sc)
                    zacc[j] += fexp2(fmaf(acc[sc][j], CSC, bias_p[j]));
        } else {
            #pragma unroll
            for (int j = 0; j < 4; ++j) {
                const int rl = rbase + j;
                const int tg = t0 + rl;
                #pragma unroll
                for (int sc = 0; sc < 4; ++sc) {
                    const int sg = tile * 64 + sc * 16 + l16;
                    int dsr = sg - tg;
                    int dc = dsr < -16 ? -16 : (dsr > 16 ? 16 : dsr);
                    zacc[j] += fexp2(fmaf(acc[sc][j], CSC, biasS[rl * 34 + dc + 16]));
                }
            }
        }
        __syncthreads();
    }
    float iZ[4];
    #pragma unroll
    for (int j = 0; j < 4; ++j) {
        float z = zacc[j];
        #pragma unroll
        for (int o = 1; o < 16; o <<= 1) z += __shfl_xor(z, o);
        iZ[j] = 1.f / z;
    }

    f32x4 oacc[4];
    {
        f32x4 z = {0.f, 0.f, 0.f, 0.f};
        #pragma unroll
        for (int dc = 0; dc < 4; ++dc) oacc[dc] = z;
    }
    float ps0[4]  = {0.f, 0.f, 0.f, 0.f};
    float ps32[4] = {0.f, 0.f, 0.f, 0.f};
    float* attnB = attng + (long)bh * T_ * T_;

    for (int tile = 0; tile < 16; ++tile) {
        stage64x64 (kg + base + (long)tile * 64 * D_, Kt, tid);
        stage64x64T(vg + base + (long)tile * 64 * D_, Vt, tid);
        __syncthreads();
        f32x4 acc[4];
        #pragma unroll
        for (int sc = 0; sc < 4; ++sc) {
            f32x4 a = {0.f, 0.f, 0.f, 0.f};
            #pragma unroll
            for (int ks = 0; ks < 2; ++ks) {
                const int r = sc * 16 + l16;
                short8 bf = *(short8*)&Kt[((r * 64 + ks * 32 + g16 * 8) ^ ((r & 7) << 3))];
                a = __builtin_amdgcn_mfma_f32_16x16x32_bf16(qfrag[ks], bf, a, 0, 0, 0);
            }
            acc[sc] = a;
        }
        #pragma unroll
        for (int j = 0; j < 4; ++j) {
            const int rl = rbase + j;
            const int tg = t0 + rl;
            #pragma unroll
            for (int sc = 0; sc < 4; ++sc) {
                const int sl = sc * 16 + l16;
                const int sg = tile * 64 + sl;
                const int dsr = sg - tg;
                int dc = dsr < -16 ? -16 : (dsr > 16 ? 16 : dsr);
                const float b = biasS[rl * 34 + dc + 16];
                const float a = fexp2(fmaf(acc[sc][j], CSC, b)) * iZ[j];
                attnB[(long)tg * T_ + sg] = a;
                QPt[((rl * 64 + sl) ^ ((rl & 7) << 3))] = f2bf(a);
                if (dsr <= -16)      ps0[j]  += a;
                else if (dsr >= 16)  ps32[j] += a;
                else                 wS[rl * 33 + dsr + 16] = a;
            }
        }
        #pragma unroll
        for (int ks = 0; ks < 2; ++ks) {
            const int rp = wv * 16 + l16;
            short8 pa = *(short8*)&QPt[((rp * 64 + ks * 32 + g16 * 8) ^ ((rp & 7) << 3))];
            #pragma unroll
            for (int dc = 0; dc < 4; ++dc) {
                const int rv = dc * 16 + l16;
                short8 vb = *(short8*)&Vt[((rv * 64 + ks * 32 + g16 * 8) ^ ((rv & 7) << 3))];
                oacc[dc] = __builtin_amdgcn_mfma_f32_16x16x32_bf16(pa, vb, oacc[dc], 0, 0, 0);
            }
        }
        __syncthreads();
    }

    float w0r[4], w32r[4];
    #pragma unroll
    for (int j = 0; j < 4; ++j) {
        float a0 = ps0[j], a2 = ps32[j];
        #pragma unroll
        for (int o = 1; o < 16; o <<= 1) {
            a0 += __shfl_xor(a0, o);
            a2 += __shfl_xor(a2, o);
        }
        w0r[j] = a0; w32r[j] = a2;
    }
    __syncthreads();

    float vals[4][4];
    #pragma unroll
    for (int j = 0; j < 4; ++j)
        #pragma unroll
        for (int dc = 0; dc < 4; ++dc)
            vals[j][dc] = oacc[dc][j]
                        + w0r[j]  * embvS[0 * 64  + dc * 16 + l16]
                        + w32r[j] * embvS[32 * 64 + dc * 16 + l16];
    for (int jj = 1; jj < 32; ++jj) {
        float e[4];
        #pragma unroll
        for (int dc = 0; dc < 4; ++dc) e[dc] = embvS[jj * 64 + dc * 16 + l16];
        #pragma unroll
        for (int j = 0; j < 4; ++j) {
            const float w = wS[(rbase + j) * 33 + jj];
            #pragma unroll
            for (int dc = 0; dc < 4; ++dc) vals[j][dc] += w * e[dc];
        }
    }
    #pragma unroll
    for (int j = 0; j < 4; ++j) {
        const int tg = t0 + rbase + j;
        #pragma unroll
        for (int dc = 0; dc < 4; ++dc)
            outg[base + (long)tg * D_ + dc * 16 + l16] = vals[j][dc];
    }
}

extern "C" void kernel_launch(void* const* d_in, const int* in_sizes, int n_in,
                              void* d_out, int out_size, void* d_ws, size_t ws_size,
                              hipStream_t stream) {
    const float* q    = (const float*)d_in[0];
    const float* k    = (const float*)d_in[1];
    const float* v    = (const float*)d_in[2];
    const float* embk = (const float*)d_in[3];
    const float* embv = (const float*)d_in[4];
    float* out  = (float*)d_out;
    float* attn = out + (long)4 * 16 * 1024 * 64;

    if (ws_size >= (size_t)16777216) {
        unsigned short* kbf = (unsigned short*)d_ws;
        unsigned short* vtb = kbf + 4194304;
        preconv<<<dim3(1024), dim3(256), 0, stream>>>(k, v, kbf, vtb);
        relattn<<<dim3(1024), dim3(256), 0, stream>>>(q, kbf, vtb, embk, embv, out, attn);
    } else {
        relattn_fb<<<dim3(1024), dim3(256), 0, stream>>>(q, k, v, embk, embv, out, attn);
    }
}

// Round 21
// 162.558 us; speedup vs baseline: 1.0220x; 1.0220x over previous
//
#include <hip/hip_runtime.h>

typedef __attribute__((ext_vector_type(8))) short short8;
typedef __attribute__((ext_vector_type(4))) float f32x4;

#define T_ 1024
#define D_ 64
#define CSC 0.18033688f   // 0.125 * log2(e)

static __device__ __forceinline__ unsigned short f2bf(float f) {
    union { float f; unsigned u; } x; x.f = f;
    unsigned r = x.u + 0x7fffu + ((x.u >> 16) & 1u);
    return (unsigned short)(r >> 16);
}
static __device__ __forceinline__ float fexp2(float x) {
    return __builtin_amdgcn_exp2f(fminf(x, 60.f));
}
// async global->LDS, 16B per lane; LDS dest is wave-uniform base + lane*16
static __device__ __forceinline__ void gload16(const unsigned short* g, unsigned short* l) {
    __builtin_amdgcn_global_load_lds(
        (__attribute__((address_space(1))) void*)g,
        (__attribute__((address_space(3))) void*)l, 16, 0, 0);
}

// ================= pre-kernel: K -> bf16, V -> V^T bf16 (into ws) ============
__global__ __launch_bounds__(256) void preconv(
    const float* __restrict__ kg, const float* __restrict__ vg,
    unsigned short* __restrict__ kbf, unsigned short* __restrict__ vtb)
{
    __shared__ float vt[64][65];
    const int tid = threadIdx.x;
    const int bh = blockIdx.x >> 4, tile = blockIdx.x & 15;
    const long eb = (long)bh * (T_ * D_) + tile * 64 * D_;
    const int r = tid >> 2, d0 = (tid & 3) * 16;

    {   // K convert (row-major bf16; main kernel pre-swizzles its source addr)
        const float* s = kg + eb + r * 64 + d0;
        f32x4 a0 = *(const f32x4*)(s + 0);
        f32x4 a1 = *(const f32x4*)(s + 4);
        f32x4 a2 = *(const f32x4*)(s + 8);
        f32x4 a3 = *(const f32x4*)(s + 12);
        short8 p0, p1;
        #pragma unroll
        for (int i = 0; i < 4; ++i) {
            p0[i]     = (short)f2bf(a0[i]); p0[4 + i] = (short)f2bf(a1[i]);
            p1[i]     = (short)f2bf(a2[i]); p1[4 + i] = (short)f2bf(a3[i]);
        }
        *(short8*)&kbf[eb + r * 64 + d0]     = p0;
        *(short8*)&kbf[eb + r * 64 + d0 + 8] = p1;
    }
    {   // V tile -> LDS transposed (fp32)
        const float* s = vg + eb + r * 64 + d0;
        f32x4 a0 = *(const f32x4*)(s + 0);
        f32x4 a1 = *(const f32x4*)(s + 4);
        f32x4 a2 = *(const f32x4*)(s + 8);
        f32x4 a3 = *(const f32x4*)(s + 12);
        #pragma unroll
        for (int i = 0; i < 4; ++i) {
            vt[d0 + i][r]      = a0[i];
            vt[d0 + 4 + i][r]  = a1[i];
            vt[d0 + 8 + i][r]  = a2[i];
            vt[d0 + 12 + i][r] = a3[i];
        }
    }
    __syncthreads();
    {   // V^T rows out (coalesced), bf16
        short8 p0, p1;
        #pragma unroll
        for (int i = 0; i < 8; ++i) {
            p0[i] = (short)f2bf(vt[r][d0 + i]);
            p1[i] = (short)f2bf(vt[r][d0 + 8 + i]);
        }
        const long vb = ((long)bh * D_ + r) * T_ + tile * 64 + d0;
        *(short8*)&vtb[vb]     = p0;
        *(short8*)&vtb[vb + 8] = p1;
    }
}

// ==== main kernel: sweep1 128-row super-tiles; sweep2 = R16 counted barrier ==
__global__ __launch_bounds__(256, 3) void relattn(
    const float* __restrict__ qg,
    const unsigned short* __restrict__ kbf,   // [bh][1024][64] bf16
    const unsigned short* __restrict__ vtb,   // [bh][64][1024] bf16 (V^T)
    const float* __restrict__ embk,
    const float* __restrict__ embv,
    float* __restrict__ outg, float* __restrict__ attng)
{
    // 49152 B -> 3 blocks/CU
    __shared__ __align__(16) unsigned char lds[49152];
    unsigned short* QPt   = (unsigned short*)(lds);           // [0,8192): Q -> P (wave-private rows)
    unsigned short* Kb    = (unsigned short*)(lds + 8192);    // [8192,24576): K dbuf (sweep2)
    unsigned short* Vb    = (unsigned short*)(lds + 24576);   // [24576,40960): V^T dbuf (sweep2)
    // sweep1: [8192,40960) = two 16 KB super-buffers (128-row K tiles)
    _Float16*       biasH = (_Float16*)(lds + 40960);         // fp16 [64][33]
    _Float16*       wS    = (_Float16*)(lds + 45184);         // fp16 [64][31]
    float*          embvS = (float*)(lds);                    // epilogue alias

    const int tid  = threadIdx.x;
    const int lane = tid & 63;
    const int wv   = tid >> 6;
    const int g16  = lane >> 4;
    const int l16  = lane & 15;
    const int rbase = wv * 16 + g16 * 4;

    const int lg = ((blockIdx.x & 7) << 7) | (blockIdx.x >> 3);
    const int bh = lg >> 4;
    const int t0 = (lg & 15) * 64;
    const int dtile = t0 >> 6;
    const long base = (long)bh * (T_ * D_);

    // per-lane pre-swizzled source offsets (elem units); same involution the
    // frag reader applies: group g at row r reads source group g^(r&7).
    int kofs0, kofs1, vofs0, vofs1;
    {
        const int gg = lane & 7, lr = lane >> 3;
        const int r0 = (wv * 2) * 8 + lr, r1 = (wv * 2 + 1) * 8 + lr;
        kofs0 = r0 * 64   + ((gg ^ (r0 & 7)) << 3);
        kofs1 = r1 * 64   + ((gg ^ (r1 & 7)) << 3);
        vofs0 = r0 * 1024 + ((gg ^ (r0 & 7)) << 3);
        vofs1 = r1 * 1024 + ((gg ^ (r1 & 7)) << 3);
    }
    const unsigned short* kbh = kbf + base;
    const unsigned short* vbh = vtb + base;

    // ---------- prologue: Q stage + wS zero ----------
    {
        const int r = tid >> 2, d0 = (tid & 3) * 16;
        const float* s = qg + base + (long)t0 * D_ + r * 64 + d0;
        f32x4 a0 = *(const f32x4*)(s + 0);
        f32x4 a1 = *(const f32x4*)(s + 4);
        f32x4 a2 = *(const f32x4*)(s + 8);
        f32x4 a3 = *(const f32x4*)(s + 12);
        short8 p0, p1;
        #pragma unroll
        for (int i = 0; i < 4; ++i) {
            p0[i]     = (short)f2bf(a0[i]); p0[4 + i] = (short)f2bf(a1[i]);
            p1[i]     = (short)f2bf(a2[i]); p1[4 + i] = (short)f2bf(a3[i]);
        }
        const int sw = (r & 7) << 3;
        *(short8*)&QPt[(r * 64 + d0)     ^ sw] = p0;
        *(short8*)&QPt[(r * 64 + d0 + 8) ^ sw] = p1;
    }
    for (int i = tid; i < 64 * 31; i += 256) wS[i] = (_Float16)0.f;
    __syncthreads();

    // issue K super-tile 0 (tiles 0,1) into super-buf 0 (hides under bias)
    {
        unsigned short* k0 = (unsigned short*)(lds + 8192) + wv * 1024;
        gload16(kbh + kofs0, k0);
        gload16(kbh + kofs1, k0 + 512);
        gload16(kbh + 4096 + kofs0, k0 + 4096);
        gload16(kbh + 4096 + kofs1, k0 + 4096 + 512);
    }

    // bias[r][j] = CSC * (q_fp32 . emb_k[j]) -> fp16
    for (int p = tid; p < 64 * 33; p += 256) {
        const int r = p / 33, j = p - r * 33;
        const float* qr = qg + base + (long)(t0 + r) * D_;
        const float* er = embk + j * D_;
        float acc = 0.f;
        #pragma unroll
        for (int d = 0; d < 64; d += 4) {
            f32x4 a = *(const f32x4*)(qr + d);
            f32x4 b = *(const f32x4*)(er + d);
            acc += a[0] * b[0] + a[1] * b[1] + a[2] * b[2] + a[3] * b[3];
        }
        biasH[r * 33 + j] = (_Float16)(acc * CSC);
    }

    short8 qfrag[2];
    {
        const int r = wv * 16 + l16;
        const int sw = (r & 7) << 3;
        qfrag[0] = *(short8*)&QPt[((r * 64 + 0  + g16 * 8) ^ sw)];
        qfrag[1] = *(short8*)&QPt[((r * 64 + 32 + g16 * 8) ^ sw)];
    }
    __syncthreads();   // biasH visible; super-tile 0 landed (vmcnt drain)

    float bias_m[4], bias_p[4];
    #pragma unroll
    for (int j = 0; j < 4; ++j) {
        bias_m[j] = (float)biasH[(rbase + j) * 33 + 0];
        bias_p[j] = (float)biasH[(rbase + j) * 33 + 32];
    }

    // ---------- sweep 1: Z only; 128-row super-tiles, 8 barriers ----------
    float zacc[4] = {0.f, 0.f, 0.f, 0.f};
    for (int s = 0; s < 8; ++s) {
        unsigned short* Kc = (unsigned short*)(lds + 8192 + ((s & 1) << 14));
        if (s < 7) {
            unsigned short* kn = (unsigned short*)(lds + 8192 + (((s + 1) & 1) << 14)) + wv * 1024;
            const unsigned short* src = kbh + (2 * s + 2) * 4096;
            gload16(src + kofs0, kn);
            gload16(src + kofs1, kn + 512);
            gload16(src + 4096 + kofs0, kn + 4096);
            gload16(src + 4096 + kofs1, kn + 4096 + 512);
        }
        #pragma unroll
        for (int half = 0; half < 2; ++half) {
            const int tile = 2 * s + half;
            unsigned short* Kt = Kc + half * 4096;
            f32x4 acc[4];
            #pragma unroll
            for (int sc = 0; sc < 4; ++sc) {
                f32x4 a = {0.f, 0.f, 0.f, 0.f};
                #pragma unroll
                for (int ks = 0; ks < 2; ++ks) {
                    const int r = sc * 16 + l16;
                    short8 bf = *(short8*)&Kt[((r * 64 + ks * 32 + g16 * 8) ^ ((r & 7) << 3))];
                    a = __builtin_amdgcn_mfma_f32_16x16x32_bf16(qfrag[ks], bf, a, 0, 0, 0);
                }
                acc[sc] = a;
            }
            if (tile < dtile - 1) {
                #pragma unroll
                for (int j = 0; j < 4; ++j)
                    #pragma unroll
                    for (int sc = 0; sc < 4; ++sc)
                        zacc[j] += fexp2(fmaf(acc[sc][j], CSC, bias_m[j]));
            } else if (tile > dtile + 1) {
                #pragma unroll
                for (int j = 0; j < 4; ++j)
                    #pragma unroll
                    for (int sc = 0; sc < 4; ++sc)
                        zacc[j] += fexp2(fmaf(acc[sc][j], CSC, bias_p[j]));
            } else {
                #pragma unroll
                for (int j = 0; j < 4; ++j) {
                    const int rl = rbase + j;
                    const int tg = t0 + rl;
                    #pragma unroll
                    for (int sc = 0; sc < 4; ++sc) {
                        const int sg = tile * 64 + sc * 16 + l16;
                        int dsr = sg - tg;
                        int dc = dsr < -16 ? -16 : (dsr > 16 ? 16 : dsr);
                        const float b = (float)biasH[rl * 33 + dc + 16];
                        zacc[j] += fexp2(fmaf(acc[sc][j], CSC, b));
                    }
                }
            }
        }
        __syncthreads();   // drains next-super loads; all waves done with Kc
    }
    float iZ[4];
    #pragma unroll
    for (int j = 0; j < 4; ++j) {
        float z = zacc[j];
        #pragma unroll
        for (int o = 1; o < 16; o <<= 1) z += __shfl_xor(z, o);
        iZ[j] = 1.f / z;
    }

    // ---------- sweep 2 prologue: issue K0,V0 ----------
    {
        unsigned short* kdst = Kb + wv * 1024;
        unsigned short* vdst = Vb + wv * 1024;
        gload16(kbh + kofs0, kdst);
        gload16(kbh + kofs1, kdst + 512);
        gload16(vbh + vofs0, vdst);
        gload16(vbh + vofs1, vdst + 512);
    }
    __syncthreads();   // K0,V0 landed

    // ---------- sweep 2: K+V dbuf, ONE counted barrier/iter (R16-validated) ----
    f32x4 oacc[4];
    {
        f32x4 z = {0.f, 0.f, 0.f, 0.f};
        #pragma unroll
        for (int dc = 0; dc < 4; ++dc) oacc[dc] = z;
    }
    float ps0[4]  = {0.f, 0.f, 0.f, 0.f};
    float ps32[4] = {0.f, 0.f, 0.f, 0.f};
    float* attnB = attng + (long)bh * T_ * T_;

    for (int tile = 0; tile < 16; ++tile) {
        unsigned short* Kc = Kb + ((tile & 1) << 12);
        unsigned short* Vc = Vb + ((tile & 1) << 12);
        if (tile < 15) {
            unsigned short* kn = Kb + (((tile + 1) & 1) << 12) + wv * 1024;
            unsigned short* vn = Vb + (((tile + 1) & 1) << 12) + wv * 1024;
            gload16(kbh + (tile + 1) * 4096 + kofs0, kn);
            gload16(kbh + (tile + 1) * 4096 + kofs1, kn + 512);
            gload16(vbh + (tile + 1) * 64 + vofs0, vn);
            gload16(vbh + (tile + 1) * 64 + vofs1, vn + 512);
        }
        __builtin_amdgcn_sched_barrier(0);   // pin issue order (vmcnt counts)

        // QK^T from Kc (landed at prev iter's barrier)
        f32x4 acc[4];
        #pragma unroll
        for (int sc = 0; sc < 4; ++sc) {
            f32x4 a = {0.f, 0.f, 0.f, 0.f};
            #pragma unroll
            for (int ks = 0; ks < 2; ++ks) {
                const int r = sc * 16 + l16;
                short8 bf = *(short8*)&Kc[((r * 64 + ks * 32 + g16 * 8) ^ ((r & 7) << 3))];
                a = __builtin_amdgcn_mfma_f32_16x16x32_bf16(qfrag[ks], bf, a, 0, 0, 0);
            }
            acc[sc] = a;
        }

        // softmax + attn stores (16 dword stores/lane — retire with 1-iter slack)
        if (tile < dtile - 1) {
            #pragma unroll
            for (int j = 0; j < 4; ++j) {
                const int rl = rbase + j;
                const int tg = t0 + rl;
                #pragma unroll
                for (int sc = 0; sc < 4; ++sc) {
                    const int sl = sc * 16 + l16;
                    const float a = fexp2(fmaf(acc[sc][j], CSC, bias_m[j])) * iZ[j];
                    attnB[(long)tg * T_ + tile * 64 + sl] = a;
                    QPt[((rl * 64 + sl) ^ ((rl & 7) << 3))] = f2bf(a);
                    ps0[j] += a;
                }
            }
        } else if (tile > dtile + 1) {
            #pragma unroll
            for (int j = 0; j < 4; ++j) {
                const int rl = rbase + j;
                const int tg = t0 + rl;
                #pragma unroll
                for (int sc = 0; sc < 4; ++sc) {
                    const int sl = sc * 16 + l16;
                    const float a = fexp2(fmaf(acc[sc][j], CSC, bias_p[j])) * iZ[j];
                    attnB[(long)tg * T_ + tile * 64 + sl] = a;
                    QPt[((rl * 64 + sl) ^ ((rl & 7) << 3))] = f2bf(a);
                    ps32[j] += a;
                }
            }
        } else {
            #pragma unroll
            for (int j = 0; j < 4; ++j) {
                const int rl = rbase + j;
                const int tg = t0 + rl;
                #pragma unroll
                for (int sc = 0; sc < 4; ++sc) {
                    const int sl = sc * 16 + l16;
                    const int sg = tile * 64 + sl;
                    const int dsr = sg - tg;
                    int dc = dsr < -16 ? -16 : (dsr > 16 ? 16 : dsr);
                    const float b = (float)biasH[rl * 33 + dc + 16];
                    const float a = fexp2(fmaf(acc[sc][j], CSC, b)) * iZ[j];
                    attnB[(long)tg * T_ + sg] = a;
                    QPt[((rl * 64 + sl) ^ ((rl & 7) << 3))] = f2bf(a);
                    if (dsr <= -16)      ps0[j]  += a;
                    else if (dsr >= 16)  ps32[j] += a;
                    else                 wS[rl * 31 + dsr + 15] = (_Float16)a;
                }
            }
        }

        // PV: A = P (own wave rows, intra-wave lgkm dep), B = V^T from Vc
        #pragma unroll
        for (int ks = 0; ks < 2; ++ks) {
            const int rp = wv * 16 + l16;
            short8 pa = *(short8*)&QPt[((rp * 64 + ks * 32 + g16 * 8) ^ ((rp & 7) << 3))];
            #pragma unroll
            for (int dc = 0; dc < 4; ++dc) {
                const int rv = dc * 16 + l16;
                short8 vb = *(short8*)&Vc[((rv * 64 + ks * 32 + g16 * 8) ^ ((rv & 7) << 3))];
                oacc[dc] = __builtin_amdgcn_mfma_f32_16x16x32_bf16(pa, vb, oacc[dc], 0, 0, 0);
            }
        }

        // ONE barrier: K/V(t+1) landed (vmcnt 16: this iter's stores in flight)
        // AND this wave's LDS reads retired (lgkmcnt 0 — the race fix).
        asm volatile("s_waitcnt vmcnt(16) lgkmcnt(0)" ::: "memory");
        __builtin_amdgcn_s_barrier();
        __builtin_amdgcn_sched_barrier(0);
    }

    // ---------- epilogue ----------
    for (int i = tid; i < 33 * 64; i += 256) embvS[i] = embv[i];

    float w0r[4], w32r[4];
    #pragma unroll
    for (int j = 0; j < 4; ++j) {
        float a0 = ps0[j], a2 = ps32[j];
        #pragma unroll
        for (int o = 1; o < 16; o <<= 1) {
            a0 += __shfl_xor(a0, o);
            a2 += __shfl_xor(a2, o);
        }
        w0r[j] = a0; w32r[j] = a2;
    }
    __syncthreads();   // embvS + wS visible (drains all residual ops)

    float vals[4][4];
    #pragma unroll
    for (int j = 0; j < 4; ++j)
        #pragma unroll
        for (int dc = 0; dc < 4; ++dc)
            vals[j][dc] = oacc[dc][j]
                        + w0r[j]  * embvS[0 * 64  + dc * 16 + l16]
                        + w32r[j] * embvS[32 * 64 + dc * 16 + l16];
    for (int jj = 1; jj < 32; ++jj) {
        float e[4];
        #pragma unroll
        for (int dc = 0; dc < 4; ++dc) e[dc] = embvS[jj * 64 + dc * 16 + l16];
        #pragma unroll
        for (int j = 0; j < 4; ++j) {
            const float w = (float)wS[(rbase + j) * 31 + jj - 1];
            #pragma unroll
            for (int dc = 0; dc < 4; ++dc) vals[j][dc] += w * e[dc];
        }
    }
    #pragma unroll
    for (int j = 0; j < 4; ++j) {
        const int tg = t0 + rbase + j;
        #pragma unroll
        for (int dc = 0; dc < 4; ++dc)
            outg[base + (long)tg * D_ + dc * 16 + l16] = vals[j][dc];
    }
}

// ================= fallback (R5-validated) if ws too small ===================
static __device__ __forceinline__ void stage64x64(const float* __restrict__ src,
                                                  unsigned short* dst, int tid) {
    const int r = tid >> 2, d0 = (tid & 3) * 16;
    const float* s = src + r * 64 + d0;
    __attribute__((aligned(16))) float tmp[16];
    *(float4*)(tmp + 0)  = *(const float4*)(s + 0);
    *(float4*)(tmp + 4)  = *(const float4*)(s + 4);
    *(float4*)(tmp + 8)  = *(const float4*)(s + 8);
    *(float4*)(tmp + 12) = *(const float4*)(s + 12);
    #pragma unroll
    for (int h = 0; h < 2; ++h) {
        short8 pk;
        #pragma unroll
        for (int i = 0; i < 8; ++i) pk[i] = (short)f2bf(tmp[h * 8 + i]);
        *(short8*)&dst[((r * 64 + d0 + h * 8) ^ ((r & 7) << 3))] = pk;
    }
}
static __device__ __forceinline__ void stage64x64T(const float* __restrict__ src,
                                                   unsigned short* dst, int tid) {
    const int r = tid >> 2, d0 = (tid & 3) * 16;
    const float* s = src + r * 64 + d0;
    __attribute__((aligned(16))) float tmp[16];
    *(float4*)(tmp + 0)  = *(const float4*)(s + 0);
    *(float4*)(tmp + 4)  = *(const float4*)(s + 4);
    *(float4*)(tmp + 8)  = *(const float4*)(s + 8);
    *(float4*)(tmp + 12) = *(const float4*)(s + 12);
    #pragma unroll
    for (int i = 0; i < 16; ++i) {
        const int dd = d0 + i;
        dst[((dd * 64 + r) ^ ((dd & 7) << 3))] = f2bf(tmp[i]);
    }
}

__global__ __launch_bounds__(256, 3) void relattn_fb(
    const float* __restrict__ qg, const float* __restrict__ kg,
    const float* __restrict__ vg, const float* __restrict__ embk,
    const float* __restrict__ embv,
    float* __restrict__ outg, float* __restrict__ attng)
{
    __shared__ __align__(16) unsigned short QPt[64 * 64];
    __shared__ __align__(16) unsigned short Kt[64 * 64];
    __shared__ __align__(16) unsigned short Vt[64 * 64];
    __shared__ float biasS[64 * 34];
    __shared__ float wS[64 * 33];
    __shared__ float embvS[33 * 64];

    const int tid  = threadIdx.x;
    const int lane = tid & 63;
    const int wv   = tid >> 6;
    const int g16  = lane >> 4;
    const int l16  = lane & 15;
    const int rbase = wv * 16 + g16 * 4;

    const int lg = ((blockIdx.x & 7) << 7) | (blockIdx.x >> 3);
    const int bh = lg >> 4;
    const int t0 = (lg & 15) * 64;
    const int dtile = t0 >> 6;
    const long base = (long)bh * (T_ * D_);

    stage64x64(qg + base + (long)t0 * D_, QPt, tid);
    for (int i = tid; i < 33 * 64; i += 256) embvS[i] = embv[i];
    for (int i = tid; i < 64 * 33; i += 256) wS[i] = 0.f;
    __syncthreads();

    for (int p = tid; p < 64 * 33; p += 256) {
        const int r = p / 33, j = p - r * 33;
        const float* qr = qg + base + (long)(t0 + r) * D_;
        const float* er = embk + j * D_;
        float acc = 0.f;
        #pragma unroll
        for (int d = 0; d < 64; d += 4) {
            f32x4 a = *(const f32x4*)(qr + d);
            f32x4 b = *(const f32x4*)(er + d);
            acc += a[0] * b[0] + a[1] * b[1] + a[2] * b[2] + a[3] * b[3];
        }
        biasS[r * 34 + j] = acc * CSC;
    }
    short8 qfrag[2];
    {
        const int r = wv * 16 + l16;
        const int sw = (r & 7) << 3;
        qfrag[0] = *(short8*)&QPt[((r * 64 + 0  + g16 * 8) ^ sw)];
        qfrag[1] = *(short8*)&QPt[((r * 64 + 32 + g16 * 8) ^ sw)];
    }
    __syncthreads();

    float bias_m[4], bias_p[4];
    #pragma unroll
    for (int j = 0; j < 4; ++j) {
        bias_m[j] = biasS[(rbase + j) * 34 + 0];
        bias_p[j] = biasS[(rbase + j) * 34 + 32];
    }

    float zacc[4] = {0.f, 0.f, 0.f, 0.f};
    for (int tile = 0; tile < 16; ++tile) {
        stage64x64(kg + base + (long)tile * 64 * D_, Kt, tid);
        __syncthreads();
        f32x4 acc[4];
        #pragma unroll
        for (int sc = 0; sc < 4; ++sc) {
            f32x4 a = {0.f, 0.f, 0.f, 0.f};
            #pragma unroll
            for (int ks = 0; ks < 2; ++ks) {
                const int r = sc * 16 + l16;
                short8 bf = *(short8*)&Kt[((r * 64 + ks * 32 + g16 * 8) ^ ((r & 7) << 3))];
                a = __builtin_amdgcn_mfma_f32_16x16x32_bf16(qfrag[ks], bf, a, 0, 0, 0);
            }
            acc[sc] = a;
        }
        if (tile < dtile - 1) {
            #pragma unroll
            for (int j = 0; j < 4; ++j)
                #pragma unroll
                for (int sc = 0; sc < 4; ++sc)
                    zacc[j] += fexp2(fmaf(acc[sc][j], CSC, bias_m[j]));
        } else if (tile > dtile + 1) {
            #pragma unroll
            for (int j = 0; j < 4; ++j)
                #pragma unroll
                for (int sc = 0; sc < 4; ++sc)
                    zacc[j] += fexp2(fmaf(acc[sc][j], CSC, bias_p[j]));
        } else {
            #pragma unroll
            for (int j = 0; j < 4; ++j) {
                const int rl = rbase + j;
                const int tg = t0 + rl;
                #pragma unroll
                for (int sc = 0; sc < 4; ++sc) {
                    const int sg = tile * 64 + sc * 16 + l16;
                    int dsr = sg - tg;
                    int dc = dsr < -16 ? -16 : (dsr > 16 ? 16 : dsr);
                    zacc[j] += fexp2(fmaf(acc[sc][j], CSC, biasS[rl * 34 + dc + 16]));
                }
            }
        }
        __syncthreads();
    }
    float iZ[4];
    #pragma unroll
    for (int j = 0; j < 4; ++j) {
        float z = zacc[j];
        #pragma unroll
        for (int o = 1; o < 16; o <<= 1) z += __shfl_xor(z, o);
        iZ[j] = 1.f / z;
    }

    f32x4 oacc[4];
    {
        f32x4 z = {0.f, 0.f, 0.f, 0.f};
        #pragma unroll
        for (int dc = 0; dc < 4; ++dc) oacc[dc] = z;
    }
    float ps0[4]  = {0.f, 0.f, 0.f, 0.f};
    float ps32[4] = {0.f, 0.f, 0.f, 0.f};
    float* attnB = attng + (long)bh * T_ * T_;

    for (int tile = 0; tile < 16; ++tile) {
        stage64x64 (kg + base + (long)tile * 64 * D_, Kt, tid);
        stage64x64T(vg + base + (long)tile * 64 * D_, Vt, tid);
        __syncthreads();
        f32x4 acc[4];
        #pragma unroll
        for (int sc = 0; sc < 4; ++sc) {
            f32x4 a = {0.f, 0.f, 0.f, 0.f};
            #pragma unroll
            for (int ks = 0; ks < 2; ++ks) {
                const int r = sc * 16 + l16;
                short8 bf = *(short8*)&Kt[((r * 64 + ks * 32 + g16 * 8) ^ ((r & 7) << 3))];
                a = __builtin_amdgcn_mfma_f32_16x16x32_bf16(qfrag[ks], bf, a, 0, 0, 0);
            }
            acc[sc] = a;
        }
        #pragma unroll
        for (int j = 0; j < 4; ++j) {
            const int rl = rbase + j;
            const int tg = t0 + rl;
            #pragma unroll
            for (int sc = 0; sc < 4; ++sc) {
                const int sl = sc * 16 + l16;
                const int sg = tile * 64 + sl;
                const int dsr = sg - tg;
                int dc = dsr < -16 ? -16 : (dsr > 16 ? 16 : dsr);
                const float b = biasS[rl * 34 + dc + 16];
                const float a = fexp2(fmaf(acc[sc][j], CSC, b)) * iZ[j];
                attnB[(long)tg * T_ + sg] = a;
                QPt[((rl * 64 + sl) ^ ((rl & 7) << 3))] = f2bf(a);
                if (dsr <= -16)      ps0[j]  += a;
                else if (dsr >= 16)  ps32[j] += a;
                else                 wS[rl * 33 + dsr + 16] = a;
            }
        }
        #pragma unroll
        for (int ks = 0; ks < 2; ++ks) {
            const int rp = wv * 16 + l16;
            short8 pa = *(short8*)&QPt[((rp * 64 + ks * 32 + g16 * 8) ^ ((rp & 7) << 3))];
            #pragma unroll
            for (int dc = 0; dc < 4; ++dc) {
                const int rv = dc * 16 + l16;
                short8 vb = *(short8*)&Vt[((rv * 64 + ks * 32 + g16 * 8) ^ ((rv & 7) << 3))];
                oacc[dc] = __builtin_amdgcn_mfma_f32_16x16x32_bf16(pa, vb, oacc[dc], 0, 0, 0);
            }
        }
        __syncthreads();
    }

    float w0r[4], w32r[4];
    #pragma unroll
    for (int j = 0; j < 4; ++j) {
        float a0 = ps0[j], a2 = ps32[j];
        #pragma unroll
        for (int o = 1; o < 16; o <<= 1) {
            a0 += __shfl_xor(a0, o);
            a2 += __shfl_xor(a2, o);
        }
        w0r[j] = a0; w32r[j] = a2;
    }
    __syncthreads();

    float vals[4][4];
    #pragma unroll
    for (int j = 0; j < 4; ++j)
        #pragma unroll
        for (int dc = 0; dc < 4; ++dc)
            vals[j][dc] = oacc[dc][j]
                        + w0r[j]  * embvS[0 * 64  + dc * 16 + l16]
                        + w32r[j] * embvS[32 * 64 + dc * 16 + l16];
    for (int jj = 1; jj < 32; ++jj) {
        float e[4];
        #pragma unroll
        for (int dc = 0; dc < 4; ++dc) e[dc] = embvS[jj * 64 + dc * 16 + l16];
        #pragma unroll
        for (int j = 0; j < 4; ++j) {
            const float w = wS[(rbase + j) * 33 + jj];
            #pragma unroll
            for (int dc = 0; dc < 4; ++dc) vals[j][dc] += w * e[dc];
        }
    }
    #pragma unroll
    for (int j = 0; j < 4; ++j) {
        const int tg = t0 + rbase + j;
        #pragma unroll
        for (int dc = 0; dc < 4; ++dc)
            outg[base + (long)tg * D_ + dc * 16 + l16] = vals[j][dc];
    }
}

extern "C" void kernel_launch(void* const* d_in, const int* in_sizes, int n_in,
                              void* d_out, int out_size, void* d_ws, size_t ws_size,
                              hipStream_t stream) {
    const float* q    = (const float*)d_in[0];
    const float* k    = (const float*)d_in[1];
    const float* v    = (const float*)d_in[2];
    const float* embk = (const float*)d_in[3];
    const float* embv = (const float*)d_in[4];
    float* out  = (float*)d_out;
    float* attn = out + (long)4 * 16 * 1024 * 64;

    if (ws_size >= (size_t)16777216) {
        unsigned short* kbf = (unsigned short*)d_ws;
        unsigned short* vtb = kbf + 4194304;
        preconv<<<dim3(1024), dim3(256), 0, stream>>>(k, v, kbf, vtb);
        relattn<<<dim3(1024), dim3(256), 0, stream>>>(q, kbf, vtb, embk, embv, out, attn);
    } else {
        relattn_fb<<<dim3(1024), dim3(256), 0, stream>>>(q, k, v, embk, embv, out, attn);
    }
}